// Round 2
// baseline (8354.612 us; speedup 1.0000x reference)
//
#include <hip/hip_runtime.h>
#include <hip/hip_bf16.h>
#include <stdint.h>

// ---------------------------------------------------------------------------
// out = net(x) + P(net(P(x))), P = swap (W,X)<->(Y,Z).  Equivariance:
// P(net(P(x);W)) = net(x; P_w(W)) -> one network, 2 weight branches.
//
// Round 2: conv2 (89% of FLOPs) on MFMA bf16 16x16x32, implicit GEMM.
//   y1p : bf16 [24w][24x][26yp][26zp][16ci]   (y,z zero-padded halo)
//   y2  : bf16 [br][24][24][24][24][16co]
//   conv2: per-(dw,dx) slab streaming into LDS, double-buffered
//          global_load_lds(16B); A rows at stride 48B (bank-friendly);
//          B pre-packed in MFMA fragment lane order.
// Workspace peak 33.8 MB (< proven 42.7 MB), branch-split per-n schedule.
// ---------------------------------------------------------------------------

#define S   24
#define S2  576
#define S3  13824
#define S4  331776

typedef __attribute__((ext_vector_type(8))) short bf16x8;
typedef __attribute__((ext_vector_type(4))) float f32x4;
typedef __attribute__((ext_vector_type(4))) int   i32x4;

__device__ __forceinline__ float bflo(uint32_t u) { return __uint_as_float(u << 16); }
__device__ __forceinline__ float bfhi(uint32_t u) { return __uint_as_float(u & 0xFFFF0000u); }
__device__ __forceinline__ uint32_t f2bf(float f) {            // RNE f32->bf16
    uint32_t u = __float_as_uint(f);
    return (u + 0x7FFFu + ((u >> 16) & 1u)) >> 16;
}
__device__ __forceinline__ int permtap(int t) {                // (kw,kx,ky,kz)->(ky,kz,kw,kx)
    int kw = t / 27, kx = (t / 9) % 3, ky = (t / 3) % 3, kz = t % 3;
    return ky * 27 + kz * 9 + kw * 3 + kx;
}

// ---------------- workspace map (bytes) ----------------
// Wp1  f32 [2br][81][16co]          @ 0       size 10368
// Wp3  f32 [2br][81][16ci]          @ 10368   size 10368
// Wp2f bf16 [2br][9ph][5s][64l][8j] @ 20736   size 92160   (ends 112896)
// y1p  bf16 [576 wx][676 yz][16]    @ 131072  size 12460032
// y2   bf16 [2br][331776][16]       @ 12591104 size 21233664  (end 33824768)
#define WP1_OFF   0
#define WP3_OFF   10368
#define WP2F_OFF  20736
#define Y1P_OFF   131072
#define Y2_OFF    12591104
#define WS_NEED   33824768

// ---------------- prep: pack weights ----------------
__global__ void prep_weights(const float* __restrict__ w1, const float* __restrict__ w2,
                             const float* __restrict__ w3,
                             float* __restrict__ Wp1, float* __restrict__ Wp3,
                             ushort* __restrict__ Wp2f) {
    const int tid = threadIdx.x;
    for (int i = tid; i < 2 * 81 * 16; i += 256) {
        int co = i & 15, t = (i >> 4) % 81, br = i / (81 * 16);
        int ts = br ? permtap(t) : t;
        Wp1[i] = w1[co * 81 + ts];
        Wp3[i] = w3[co * 81 + ts];   // for Wp3, "co" is really ci (w3: [1][16][81])
    }
    for (int i = tid; i < 46080; i += 256) {
        int j = i & 7, l = (i >> 3) & 63, idx = i >> 9;
        int s = idx % 5, ph = (idx / 5) % 9, br = idx / 45;
        int tapl = 2 * s + (l >> 5);
        int co = l & 15, ci = ((l >> 4) & 1) * 8 + j;
        ushort v = 0;
        if (tapl < 9) {
            int dw = ph / 3, dx = ph % 3, dy = tapl / 3, dz = tapl % 3;
            int t = dw * 27 + dx * 9 + dy * 3 + dz;
            int ts = br ? permtap(t) : t;
            v = (ushort)f2bf(w2[(co * 16 + ci) * 81 + ts]);
        }
        Wp2f[i] = v;
    }
}

// ---------------- zero fill (y1p halo init) ----------------
__global__ void zero_ws(uint4* __restrict__ p, int n4) {
    int i = blockIdx.x * blockDim.x + threadIdx.x;
    int stride = gridDim.x * blockDim.x;
    for (; i < n4; i += stride) p[i] = make_uint4(0u, 0u, 0u, 0u);
}

// ---------------- conv1: x (1ch f32) -> y1p (16ch bf16, padded) ----------------
// grid 576 = (w,x) planes; block 576 threads = (y,z); per (n,br).
__global__ __launch_bounds__(576) void conv1_plane(
    const float* __restrict__ xn, const float* __restrict__ Wb,
    const float* __restrict__ b1, uint32_t* __restrict__ y1p) {
    __shared__ float xl[9 * 676];
    const int tid = threadIdx.x;
    const int w = blockIdx.x / 24, xx = blockIdx.x % 24;
    for (int g = tid; g < 6084; g += 576) {
        int wi = g / 2028, r1 = g - wi * 2028;
        int xi = r1 / 676, r2 = r1 - xi * 676;
        int yp = r2 / 26, zp = r2 - yp * 26;
        int ws_ = w + wi - 1, xs = xx + xi - 1, ys = yp - 1, zs = zp - 1;
        float v = 0.f;
        if ((unsigned)ws_ < 24u && (unsigned)xs < 24u && (unsigned)ys < 24u && (unsigned)zs < 24u)
            v = xn[((ws_ * 24 + xs) * 24 + ys) * 24 + zs];
        xl[g] = v;
    }
    __syncthreads();
    const int yy = tid / 24, zz = tid - yy * 24;
    float acc[16];
#pragma unroll
    for (int c = 0; c < 16; ++c) acc[c] = 0.f;
#pragma unroll 1
    for (int dw = 0; dw < 3; ++dw)
#pragma unroll 1
        for (int dx = 0; dx < 3; ++dx) {
            const float* xp = &xl[(dw * 3 + dx) * 676];
#pragma unroll
            for (int dy = 0; dy < 3; ++dy)
#pragma unroll
                for (int dz = 0; dz < 3; ++dz) {
                    float xv = xp[(yy + dy) * 26 + (zz + dz)];
                    const float* wt = &Wb[(((dw * 3 + dx) * 3 + dy) * 3 + dz) << 4];
#pragma unroll
                    for (int c = 0; c < 16; ++c) acc[c] = fmaf(xv, wt[c], acc[c]);
                }
        }
    uint32_t pk[8];
#pragma unroll
    for (int cp = 0; cp < 8; ++cp) {
        float a = fmaxf(acc[2 * cp]     + b1[2 * cp],     0.f);
        float b = fmaxf(acc[2 * cp + 1] + b1[2 * cp + 1], 0.f);
        pk[cp] = f2bf(a) | (f2bf(b) << 16);
    }
    uint32_t* dst = y1p + ((size_t)((w * 24 + xx) * 26 + yy + 1) * 26 + zz + 1) * 8;
    *(uint4*)dst       = make_uint4(pk[0], pk[1], pk[2], pk[3]);
    *(uint4*)(dst + 4) = make_uint4(pk[4], pk[5], pk[6], pk[7]);
}

// ---------------- conv2: MFMA implicit GEMM ----------------
// grid 1728 = 24w x 24x x 3yg; block 256 = 4 waves; wave: (2y x 24z) = 3 M-tiles.
// LDS ring: [A 780 granules (rows stride 48B)][B 320 granules] x2.
#define RING_STRIDE 17600
#define B_OFF 12480

__global__ __launch_bounds__(256) void conv2_mfma(
    const char* __restrict__ y1p, const char* __restrict__ Wp2f_br,
    const float* __restrict__ b2, ushort* __restrict__ y2b) {
    __shared__ char lds[2 * RING_STRIDE];
    const int tid = threadIdx.x, lane = tid & 63, wid = tid >> 6;
    const int b = blockIdx.x;
    const int w = b / 72, r0 = b % 72, xx = r0 / 3, y0 = (r0 % 3) * 8;

    const int h = (lane >> 4) & 1;
    const bool th = lane >= 32;
    const int pyA = (lane >> 3) & 1, pzA = lane & 7;
    int aoffs[9];
#pragma unroll
    for (int t = 0; t < 9; ++t) {
        int dy = t / 3, dz = t % 3;
        aoffs[t] = ((2 * wid + pyA + dy) * 26 + (pzA + dz)) * 48 + h * 16;
    }
    f32x4 acc[3];
#pragma unroll
    for (int m = 0; m < 3; ++m) acc[m] = f32x4{0.f, 0.f, 0.f, 0.f};

#define STAGE(ph_, rb_) do {                                                        \
    int dw_ = (ph_) / 3, dx_ = (ph_) % 3;                                           \
    int wc_ = min(max(w + dw_ - 1, 0), 23), xc_ = min(max(xx + dx_ - 1, 0), 23);    \
    const char* inpl_ = y1p + (size_t)((wc_ * 24 + xc_) * 676 + y0 * 26) * 32;      \
    const char* wsl_  = Wp2f_br + (ph_) * 5120;                                     \
    _Pragma("unroll")                                                               \
    for (int it_ = 0; it_ < 5; ++it_) {                                             \
        int g_ = tid + it_ * 256;                                                   \
        if (g_ < 1100) {                                                            \
            int row_ = g_ / 3, part_ = g_ - row_ * 3;                               \
            const char* src_ = (g_ < 780)                                           \
                ? (inpl_ + row_ * 32 + (part_ & 1) * 16)                            \
                : (wsl_ + (g_ - 780) * 16);                                         \
            __builtin_amdgcn_global_load_lds(                                       \
                (const __attribute__((address_space(1))) void*)src_,                \
                (__attribute__((address_space(3))) void*)                           \
                    (lds + (rb_) + ((tid & ~63) + it_ * 256) * 16),                 \
                16, 0, 0);                                                          \
        }                                                                           \
    }                                                                               \
} while (0)

    STAGE(0, 0);
    int ring = 0;
#pragma unroll 1
    for (int ph = 0; ph < 9; ++ph) {
        __syncthreads();                       // drains vmcnt: buf[ring] ready; all waves done with other buf
        if (ph < 8) STAGE(ph + 1, ring ^ RING_STRIDE);
        int dw = ph / 3, dx = ph % 3;
        bool valid = ((unsigned)(w + dw - 1) < 24u) && ((unsigned)(xx + dx - 1) < 24u);
        if (valid) {
#pragma unroll
            for (int s = 0; s < 5; ++s) {
                i32x4 bvr = *(const i32x4*)(lds + ring + B_OFF + s * 1024 + lane * 16);
                int t0 = aoffs[2 * s];
                int t1 = aoffs[(2 * s + 1 < 9) ? (2 * s + 1) : 8];
                int asel = th ? t1 : t0;
                const char* ap = lds + ring + asel;
#pragma unroll
                for (int m = 0; m < 3; ++m) {
                    i32x4 avr = *(const i32x4*)(ap + m * 384);
                    acc[m] = __builtin_amdgcn_mfma_f32_16x16x32_bf16(
                        __builtin_bit_cast(bf16x8, avr),
                        __builtin_bit_cast(bf16x8, bvr), acc[m], 0, 0, 0);
                }
            }
        }
        ring ^= RING_STRIDE;
    }
#undef STAGE

    // epilogue: D row p=(lane>>4)*4+r, col=lane&15
    const int co = lane & 15;
    const float bb = b2[co];
    const int py = (lane >> 5) & 1, c4 = ((lane >> 4) & 1) * 4;
    const size_t rowb = ((size_t)(w * 24 + xx) * 24 + (y0 + 2 * wid + py)) * 24;
#pragma unroll
    for (int m = 0; m < 3; ++m)
#pragma unroll
        for (int r = 0; r < 4; ++r) {
            float v = fmaxf(acc[m][r] + bb, 0.f);
            y2b[(rowb + m * 8 + c4 + r) * 16 + co] = (ushort)f2bf(v);
        }
}

// ---------------- conv3: y2 (16ch x 2br) -> out (f32) ----------------
__device__ __forceinline__ float dot16(uint4 u0, uint4 u1, const float* __restrict__ wt, float a) {
    a = fmaf(bflo(u0.x), wt[0], a);  a = fmaf(bfhi(u0.x), wt[1], a);
    a = fmaf(bflo(u0.y), wt[2], a);  a = fmaf(bfhi(u0.y), wt[3], a);
    a = fmaf(bflo(u0.z), wt[4], a);  a = fmaf(bfhi(u0.z), wt[5], a);
    a = fmaf(bflo(u0.w), wt[6], a);  a = fmaf(bfhi(u0.w), wt[7], a);
    a = fmaf(bflo(u1.x), wt[8], a);  a = fmaf(bfhi(u1.x), wt[9], a);
    a = fmaf(bflo(u1.y), wt[10], a); a = fmaf(bfhi(u1.y), wt[11], a);
    a = fmaf(bflo(u1.z), wt[12], a); a = fmaf(bfhi(u1.z), wt[13], a);
    a = fmaf(bflo(u1.w), wt[14], a); a = fmaf(bfhi(u1.w), wt[15], a);
    return a;
}

__global__ __launch_bounds__(576) void conv3_plane(
    const uint32_t* __restrict__ y2, const float* __restrict__ Wp3,
    const float* __restrict__ b3, float* __restrict__ outn) {
    const int tid = threadIdx.x;
    const int w = blockIdx.x / 24, xx = blockIdx.x % 24;
    const int yy = tid / 24, zz = tid - yy * 24;
    float a0 = 0.f, a1 = 0.f;
#pragma unroll 1
    for (int dw = 0; dw < 3; ++dw) {
        int ws_ = w + dw - 1; if ((unsigned)ws_ >= 24u) continue;
#pragma unroll 1
        for (int dx = 0; dx < 3; ++dx) {
            int xs = xx + dx - 1; if ((unsigned)xs >= 24u) continue;
            const size_t plane = (size_t)(ws_ * 24 + xs) * 576;
#pragma unroll
            for (int dy = 0; dy < 3; ++dy)
#pragma unroll
                for (int dz = 0; dz < 3; ++dz) {
                    int ys = yy + dy - 1, zs = zz + dz - 1;
                    bool ok = (unsigned)ys < 24u && (unsigned)zs < 24u;
                    int t = ((dw * 3 + dx) * 3 + dy) * 3 + dz;
                    size_t ro = (plane + ys * 24 + zs) * 8;
                    uint4 z4 = make_uint4(0u, 0u, 0u, 0u);
                    uint4 u0 = ok ? *(const uint4*)(y2 + ro)     : z4;
                    uint4 u1 = ok ? *(const uint4*)(y2 + ro + 4) : z4;
                    a0 = dot16(u0, u1, &Wp3[t << 4], a0);
                    uint4 v0 = ok ? *(const uint4*)(y2 + (size_t)S4 * 8 + ro)     : z4;
                    uint4 v1 = ok ? *(const uint4*)(y2 + (size_t)S4 * 8 + ro + 4) : z4;
                    a1 = dot16(v0, v1, &Wp3[(81 + t) << 4], a1);
                }
        }
    }
    const float bias = b3[0];
    outn[((w * 24 + xx) * 24 + yy) * 24 + zz] =
        fmaxf(a0 + bias, 0.f) + fmaxf(a1 + bias, 0.f);
}

extern "C" void kernel_launch(void* const* d_in, const int* in_sizes, int n_in,
                              void* d_out, int out_size, void* d_ws, size_t ws_size,
                              hipStream_t stream) {
    const float* x  = (const float*)d_in[0];
    const float* w1 = (const float*)d_in[1];
    const float* b1 = (const float*)d_in[2];
    const float* w2 = (const float*)d_in[3];
    const float* b2 = (const float*)d_in[4];
    const float* w3 = (const float*)d_in[5];
    const float* b3 = (const float*)d_in[6];
    float* out = (float*)d_out;
    char* ws = (char*)d_ws;
    if (ws_size < WS_NEED) return;   // ws was >= 42.7MB in round 1; we need 33.8MB

    float*  Wp1  = (float*)(ws + WP1_OFF);
    float*  Wp3  = (float*)(ws + WP3_OFF);
    ushort* Wp2f = (ushort*)(ws + WP2F_OFF);
    uint32_t* y1p_u32 = (uint32_t*)(ws + Y1P_OFF);
    const char* y1p_b = (const char*)(ws + Y1P_OFF);
    ushort* y2 = (ushort*)(ws + Y2_OFF);

    prep_weights<<<1, 256, 0, stream>>>(w1, w2, w3, Wp1, Wp3, Wp2f);
    zero_ws<<<1024, 256, 0, stream>>>((uint4*)(ws + Y1P_OFF), 12460032 / 16);

    for (int n = 0; n < 8; ++n) {
        for (int br = 0; br < 2; ++br) {
            conv1_plane<<<576, 576, 0, stream>>>(
                x + (size_t)n * S4, Wp1 + br * 81 * 16, b1, y1p_u32);
            conv2_mfma<<<1728, 256, 0, stream>>>(
                y1p_b, (const char*)(ws + WP2F_OFF) + br * 46080, b2,
                y2 + (size_t)br * S4 * 16);
        }
        conv3_plane<<<576, 576, 0, stream>>>(
            (const uint32_t*)y2, Wp3, b3, out + (size_t)n * S4);
    }
}

// Round 3
// 3282.244 us; speedup vs baseline: 2.5454x; 2.5454x over previous
//
#include <hip/hip_runtime.h>
#include <hip/hip_bf16.h>
#include <stdint.h>

// ---------------------------------------------------------------------------
// out = net(x) + P(net(P(x))), P = swap (W,X)<->(Y,Z).  Equivariance:
// P(net(P(x);W)) = net(x; P_w(W)) -> one network, 2 weight branches.
//
// Round 3: fix conv3 (was 90% of runtime, latency-bound).
//   y2 layout now [pos][2br][16co] bf16 (64-B records; lane pairs split one
//   cache line).  conv3 = z-line register rolling: thread owns 6 z-outputs of
//   one (w,x,y,br); per (dw,dx,dy) streams 8 contiguous rows, each row feeds
//   3 accumulators (dz reuse in regs).  Branch sum via __shfl_xor(1).
//   ws-adaptive: if ws fits y2 for all 8 n, conv3 runs as ONE big dispatch.
// ---------------------------------------------------------------------------

#define S   24
#define S2  576
#define S3  13824
#define S4  331776

typedef __attribute__((ext_vector_type(8))) short bf16x8;
typedef __attribute__((ext_vector_type(4))) float f32x4;
typedef __attribute__((ext_vector_type(4))) int   i32x4;

__device__ __forceinline__ float bflo(uint32_t u) { return __uint_as_float(u << 16); }
__device__ __forceinline__ float bfhi(uint32_t u) { return __uint_as_float(u & 0xFFFF0000u); }
__device__ __forceinline__ uint32_t f2bf(float f) {            // RNE f32->bf16
    uint32_t u = __float_as_uint(f);
    return (u + 0x7FFFu + ((u >> 16) & 1u)) >> 16;
}
__device__ __forceinline__ int permtap(int t) {                // (kw,kx,ky,kz)->(ky,kz,kw,kx)
    int kw = t / 27, kx = (t / 9) % 3, ky = (t / 3) % 3, kz = t % 3;
    return ky * 27 + kz * 9 + kw * 3 + kx;
}

// ---------------- workspace map (bytes) ----------------
// Wp1  f32 [2br][81][16co]          @ 0        10368
// Wp3  f32 [2br][81][16ci]          @ 10368    10368
// Wp2f bf16 [2br][9ph][5s][64l][8j] @ 20736    92160   (ends 112896)
// y1p  bf16 [576 wx][676 yz][16]    @ 131072   12460032
// y2   bf16 [N][331776][2br][16]    @ 12591104 N*21233664
#define WP1_OFF   0
#define WP3_OFF   10368
#define WP2F_OFF  20736
#define Y1P_OFF   131072
#define Y2_OFF    12591104
#define Y2_PER_N  21233664ull
#define WS_SMALL  (Y2_OFF + Y2_PER_N)          // 33.8 MB
#define WS_BIG    (Y2_OFF + 8 * Y2_PER_N)      // 182.5 MB

// ---------------- prep: pack weights ----------------
__global__ void prep_weights(const float* __restrict__ w1, const float* __restrict__ w2,
                             const float* __restrict__ w3,
                             float* __restrict__ Wp1, float* __restrict__ Wp3,
                             ushort* __restrict__ Wp2f) {
    const int tid = threadIdx.x;
    for (int i = tid; i < 2 * 81 * 16; i += 256) {
        int co = i & 15, t = (i >> 4) % 81, br = i / (81 * 16);
        int ts = br ? permtap(t) : t;
        Wp1[i] = w1[co * 81 + ts];
        Wp3[i] = w3[co * 81 + ts];   // for Wp3, "co" is really ci (w3: [1][16][81])
    }
    for (int i = tid; i < 46080; i += 256) {
        int j = i & 7, l = (i >> 3) & 63, idx = i >> 9;
        int s = idx % 5, ph = (idx / 5) % 9, br = idx / 45;
        int tapl = 2 * s + (l >> 5);
        int co = l & 15, ci = ((l >> 4) & 1) * 8 + j;
        ushort v = 0;
        if (tapl < 9) {
            int dw = ph / 3, dx = ph % 3, dy = tapl / 3, dz = tapl % 3;
            int t = dw * 27 + dx * 9 + dy * 3 + dz;
            int ts = br ? permtap(t) : t;
            v = (ushort)f2bf(w2[(co * 16 + ci) * 81 + ts]);
        }
        Wp2f[i] = v;
    }
}

// ---------------- zero fill (y1p halo init) ----------------
__global__ void zero_ws(uint4* __restrict__ p, int n4) {
    int i = blockIdx.x * blockDim.x + threadIdx.x;
    int stride = gridDim.x * blockDim.x;
    for (; i < n4; i += stride) p[i] = make_uint4(0u, 0u, 0u, 0u);
}

// ---------------- conv1: x (1ch f32) -> y1p (16ch bf16, padded) ----------------
__global__ __launch_bounds__(576) void conv1_plane(
    const float* __restrict__ xn, const float* __restrict__ Wb,
    const float* __restrict__ b1, uint32_t* __restrict__ y1p) {
    __shared__ float xl[9 * 676];
    const int tid = threadIdx.x;
    const int w = blockIdx.x / 24, xx = blockIdx.x % 24;
    for (int g = tid; g < 6084; g += 576) {
        int wi = g / 2028, r1 = g - wi * 2028;
        int xi = r1 / 676, r2 = r1 - xi * 676;
        int yp = r2 / 26, zp = r2 - yp * 26;
        int ws_ = w + wi - 1, xs = xx + xi - 1, ys = yp - 1, zs = zp - 1;
        float v = 0.f;
        if ((unsigned)ws_ < 24u && (unsigned)xs < 24u && (unsigned)ys < 24u && (unsigned)zs < 24u)
            v = xn[((ws_ * 24 + xs) * 24 + ys) * 24 + zs];
        xl[g] = v;
    }
    __syncthreads();
    const int yy = tid / 24, zz = tid - yy * 24;
    float acc[16];
#pragma unroll
    for (int c = 0; c < 16; ++c) acc[c] = 0.f;
#pragma unroll 1
    for (int dw = 0; dw < 3; ++dw)
#pragma unroll 1
        for (int dx = 0; dx < 3; ++dx) {
            const float* xp = &xl[(dw * 3 + dx) * 676];
#pragma unroll
            for (int dy = 0; dy < 3; ++dy)
#pragma unroll
                for (int dz = 0; dz < 3; ++dz) {
                    float xv = xp[(yy + dy) * 26 + (zz + dz)];
                    const float* wt = &Wb[(((dw * 3 + dx) * 3 + dy) * 3 + dz) << 4];
#pragma unroll
                    for (int c = 0; c < 16; ++c) acc[c] = fmaf(xv, wt[c], acc[c]);
                }
        }
    uint32_t pk[8];
#pragma unroll
    for (int cp = 0; cp < 8; ++cp) {
        float a = fmaxf(acc[2 * cp]     + b1[2 * cp],     0.f);
        float b = fmaxf(acc[2 * cp + 1] + b1[2 * cp + 1], 0.f);
        pk[cp] = f2bf(a) | (f2bf(b) << 16);
    }
    uint32_t* dst = y1p + ((size_t)((w * 24 + xx) * 26 + yy + 1) * 26 + zz + 1) * 8;
    *(uint4*)dst       = make_uint4(pk[0], pk[1], pk[2], pk[3]);
    *(uint4*)(dst + 4) = make_uint4(pk[4], pk[5], pk[6], pk[7]);
}

// ---------------- conv2: MFMA implicit GEMM ----------------
#define RING_STRIDE 17600
#define B_OFF 12480

__global__ __launch_bounds__(256) void conv2_mfma(
    const char* __restrict__ y1p, const char* __restrict__ Wp2f_br,
    const float* __restrict__ b2, ushort* __restrict__ y2b) {
    __shared__ char lds[2 * RING_STRIDE];
    const int tid = threadIdx.x, lane = tid & 63, wid = tid >> 6;
    const int b = blockIdx.x;
    const int w = b / 72, r0 = b % 72, xx = r0 / 3, y0 = (r0 % 3) * 8;

    const int h = (lane >> 4) & 1;
    const bool th = lane >= 32;
    const int pyA = (lane >> 3) & 1, pzA = lane & 7;
    int aoffs[9];
#pragma unroll
    for (int t = 0; t < 9; ++t) {
        int dy = t / 3, dz = t % 3;
        aoffs[t] = ((2 * wid + pyA + dy) * 26 + (pzA + dz)) * 48 + h * 16;
    }
    f32x4 acc[3];
#pragma unroll
    for (int m = 0; m < 3; ++m) acc[m] = f32x4{0.f, 0.f, 0.f, 0.f};

#define STAGE(ph_, rb_) do {                                                        \
    int dw_ = (ph_) / 3, dx_ = (ph_) % 3;                                           \
    int wc_ = min(max(w + dw_ - 1, 0), 23), xc_ = min(max(xx + dx_ - 1, 0), 23);    \
    const char* inpl_ = y1p + (size_t)((wc_ * 24 + xc_) * 676 + y0 * 26) * 32;      \
    const char* wsl_  = Wp2f_br + (ph_) * 5120;                                     \
    _Pragma("unroll")                                                               \
    for (int it_ = 0; it_ < 5; ++it_) {                                             \
        int g_ = tid + it_ * 256;                                                   \
        if (g_ < 1100) {                                                            \
            int row_ = g_ / 3, part_ = g_ - row_ * 3;                               \
            const char* src_ = (g_ < 780)                                           \
                ? (inpl_ + row_ * 32 + (part_ & 1) * 16)                            \
                : (wsl_ + (g_ - 780) * 16);                                         \
            __builtin_amdgcn_global_load_lds(                                       \
                (const __attribute__((address_space(1))) void*)src_,                \
                (__attribute__((address_space(3))) void*)                           \
                    (lds + (rb_) + ((tid & ~63) + it_ * 256) * 16),                 \
                16, 0, 0);                                                          \
        }                                                                           \
    }                                                                               \
} while (0)

    STAGE(0, 0);
    int ring = 0;
#pragma unroll 1
    for (int ph = 0; ph < 9; ++ph) {
        __syncthreads();
        if (ph < 8) STAGE(ph + 1, ring ^ RING_STRIDE);
        int dw = ph / 3, dx = ph % 3;
        bool valid = ((unsigned)(w + dw - 1) < 24u) && ((unsigned)(xx + dx - 1) < 24u);
        if (valid) {
#pragma unroll
            for (int s = 0; s < 5; ++s) {
                i32x4 bvr = *(const i32x4*)(lds + ring + B_OFF + s * 1024 + lane * 16);
                int t0 = aoffs[2 * s];
                int t1 = aoffs[(2 * s + 1 < 9) ? (2 * s + 1) : 8];
                int asel = th ? t1 : t0;
                const char* ap = lds + ring + asel;
#pragma unroll
                for (int m = 0; m < 3; ++m) {
                    i32x4 avr = *(const i32x4*)(ap + m * 384);
                    acc[m] = __builtin_amdgcn_mfma_f32_16x16x32_bf16(
                        __builtin_bit_cast(bf16x8, avr),
                        __builtin_bit_cast(bf16x8, bvr), acc[m], 0, 0, 0);
                }
            }
        }
        ring ^= RING_STRIDE;
    }
#undef STAGE

    // epilogue: D row p=(lane>>4)*4+r, col=lane&15; y2 record stride 32 ushorts
    const int co = lane & 15;
    const float bb = b2[co];
    const int py = (lane >> 5) & 1, c4 = ((lane >> 4) & 1) * 4;
    const size_t rowb = ((size_t)(w * 24 + xx) * 24 + (y0 + 2 * wid + py)) * 24;
#pragma unroll
    for (int m = 0; m < 3; ++m)
#pragma unroll
        for (int r = 0; r < 4; ++r) {
            float v = fmaxf(acc[m][r] + bb, 0.f);
            y2b[(rowb + m * 8 + c4 + r) * 32 + co] = (ushort)f2bf(v);
        }
}

// ---------------- conv3: z-line register rolling ----------------
// thread = (n, line(w,x,y), quarter q, branch br); 6 outputs along z.
// y2: [n][pos][2br][16ch] bf16 -> 16 u32 per pos.
__global__ __launch_bounds__(256) void conv3_lines(
    const uint32_t* __restrict__ y2, const float* __restrict__ Wp3g,
    const float* __restrict__ b3, float* __restrict__ out) {
    __shared__ float Wl[2 * 81 * 16];
    const int tid = threadIdx.x;
    for (int i = tid; i < 2592; i += 256) Wl[i] = Wp3g[i];
    __syncthreads();

    const int gtid = blockIdx.x * 256 + tid;
    const int n   = gtid / 110592;
    const int rem = gtid % 110592;
    const int br  = rem & 1;
    const int q   = (rem >> 1) & 3;
    const int line = rem >> 3;                 // [0, 13824)
    const int y = line % 24, xx = (line / 24) % 24, w = line / 576;
    const int z0 = q * 6;

    const uint32_t* y2n = y2 + (size_t)n * S4 * 16;
    float acc[6];
#pragma unroll
    for (int j = 0; j < 6; ++j) acc[j] = 0.f;

#pragma unroll 1
    for (int dw = 0; dw < 3; ++dw) {
        const int ws_ = w + dw - 1; const bool okw = (unsigned)ws_ < 24u;
#pragma unroll 1
        for (int dx = 0; dx < 3; ++dx) {
            const int xs = xx + dx - 1; const bool okx = okw && (unsigned)xs < 24u;
#pragma unroll 1
            for (int dy = 0; dy < 3; ++dy) {
                const int ys = y + dy - 1; const bool okp = okx && (unsigned)ys < 24u;
                const int tb = ((dw * 3 + dx) * 3 + dy) * 3;
                f32x4 wv[3][4];
#pragma unroll
                for (int dz = 0; dz < 3; ++dz) {
                    const f32x4* wrow = (const f32x4*)&Wl[(br * 81 + tb + dz) << 4];
#pragma unroll
                    for (int k = 0; k < 4; ++k) wv[dz][k] = wrow[k];
                }
                const uint32_t* rp = y2n +
                    ((long)((ws_ * 24 + xs) * 24 + ys) * 24 + z0 - 1) * 16 + br * 8;
#pragma unroll
                for (int r = 0; r < 8; ++r) {
                    const int zs = z0 - 1 + r;
                    const bool ok = okp && (unsigned)zs < 24u;
                    const uint4 zz4 = make_uint4(0u, 0u, 0u, 0u);
                    uint4 u0 = ok ? *(const uint4*)(rp + r * 16)     : zz4;
                    uint4 u1 = ok ? *(const uint4*)(rp + r * 16 + 4) : zz4;
                    float v[16];
                    v[0]=bflo(u0.x); v[1]=bfhi(u0.x); v[2]=bflo(u0.y); v[3]=bfhi(u0.y);
                    v[4]=bflo(u0.z); v[5]=bfhi(u0.z); v[6]=bflo(u0.w); v[7]=bfhi(u0.w);
                    v[8]=bflo(u1.x); v[9]=bfhi(u1.x); v[10]=bflo(u1.y); v[11]=bfhi(u1.y);
                    v[12]=bflo(u1.z); v[13]=bfhi(u1.z); v[14]=bflo(u1.w); v[15]=bfhi(u1.w);
#pragma unroll
                    for (int dz = 0; dz < 3; ++dz) {
                        const int j = r - dz;
                        if (j >= 0 && j < 6) {
#pragma unroll
                            for (int ci = 0; ci < 16; ++ci)
                                acc[j] = fmaf(v[ci], wv[dz][ci >> 2][ci & 3], acc[j]);
                        }
                    }
                }
            }
        }
    }
    const float bias = b3[0];
    float* op = out + (size_t)n * S4 + ((w * 24 + xx) * 24 + y) * 24 + z0;
#pragma unroll
    for (int j = 0; j < 6; ++j) {
        float v = fmaxf(acc[j] + bias, 0.f);
        float o = __shfl_xor(v, 1);
        if (!br) op[j] = v + o;
    }
}

extern "C" void kernel_launch(void* const* d_in, const int* in_sizes, int n_in,
                              void* d_out, int out_size, void* d_ws, size_t ws_size,
                              hipStream_t stream) {
    const float* x  = (const float*)d_in[0];
    const float* w1 = (const float*)d_in[1];
    const float* b1 = (const float*)d_in[2];
    const float* w2 = (const float*)d_in[3];
    const float* b2 = (const float*)d_in[4];
    const float* w3 = (const float*)d_in[5];
    const float* b3 = (const float*)d_in[6];
    float* out = (float*)d_out;
    char* ws = (char*)d_ws;
    if (ws_size < WS_SMALL) return;

    float*  Wp1  = (float*)(ws + WP1_OFF);
    float*  Wp3  = (float*)(ws + WP3_OFF);
    ushort* Wp2f = (ushort*)(ws + WP2F_OFF);
    uint32_t* y1p_u32 = (uint32_t*)(ws + Y1P_OFF);
    const char* y1p_b = (const char*)(ws + Y1P_OFF);

    prep_weights<<<1, 256, 0, stream>>>(w1, w2, w3, Wp1, Wp3, Wp2f);
    zero_ws<<<1024, 256, 0, stream>>>((uint4*)(ws + Y1P_OFF), 12460032 / 16);

    const bool big = (ws_size >= WS_BIG);
    const int NB = big ? 8 : 1;                  // n's resident in y2
    for (int n = 0; n < 8; ++n) {
        ushort* y2n = (ushort*)(ws + Y2_OFF + (size_t)(big ? n : 0) * Y2_PER_N);
        for (int br = 0; br < 2; ++br) {
            conv1_plane<<<576, 576, 0, stream>>>(
                x + (size_t)n * S4, Wp1 + br * 81 * 16, b1, y1p_u32);
            conv2_mfma<<<1728, 256, 0, stream>>>(
                y1p_b, (const char*)(ws + WP2F_OFF) + br * 46080, b2, y2n + br * 16);
        }
        if (!big) {
            conv3_lines<<<432, 256, 0, stream>>>(
                (const uint32_t*)y2n, Wp3, b3, out + (size_t)n * S4);
        }
    }
    if (big) {
        conv3_lines<<<3456, 256, 0, stream>>>(
            (const uint32_t*)(ws + Y2_OFF), Wp3, b3, out);
    }
}

// Round 4
// 1933.259 us; speedup vs baseline: 4.3215x; 1.6978x over previous
//
#include <hip/hip_runtime.h>
#include <hip/hip_bf16.h>
#include <stdint.h>

// ---------------------------------------------------------------------------
// out = net(x) + P(net(P(x))), P = swap (W,X)<->(Y,Z).  Equivariance:
// P(net(P(x);W)) = net(x; P_w(W)) -> one network, 2 weight branches.
//
// Round 4: conv3 plane-blocked LDS staging (was 71% of runtime, latency-bound
// with 3.8x HBM overfetch).  Block = output (w,x) plane; 9 (dw,dx) phases
// stage the input plane (both branches, 36.9KB) into LDS cells of 80B
// (64B data + 16B pad -> conflict-free b128 reads).  Per-n conv3 right after
// conv2 so y2_n (21MB) is L2-resident.  XCD-swizzled block order.
// conv1/conv2 do both branches per dispatch.  WS = 46.3 MB.
// ---------------------------------------------------------------------------

#define S   24
#define S2  576
#define S3  13824
#define S4  331776

typedef __attribute__((ext_vector_type(8))) short bf16x8;
typedef __attribute__((ext_vector_type(4))) float f32x4;
typedef __attribute__((ext_vector_type(4))) int   i32x4;

__device__ __forceinline__ float bflo(uint32_t u) { return __uint_as_float(u << 16); }
__device__ __forceinline__ float bfhi(uint32_t u) { return __uint_as_float(u & 0xFFFF0000u); }
__device__ __forceinline__ uint32_t f2bf(float f) {            // RNE f32->bf16
    uint32_t u = __float_as_uint(f);
    return (u + 0x7FFFu + ((u >> 16) & 1u)) >> 16;
}
__device__ __forceinline__ int permtap(int t) {                // (kw,kx,ky,kz)->(ky,kz,kw,kx)
    int kw = t / 27, kx = (t / 9) % 3, ky = (t / 3) % 3, kz = t % 3;
    return ky * 27 + kz * 9 + kw * 3 + kx;
}

// ---------------- workspace map (bytes) ----------------
// Wp1  f32 [2br][81][16co]          @ 0        10368
// Wp3  f32 [2br][81][16ci]          @ 10368    10368
// Wp2f bf16 [2br][9ph][5s][64l][8j] @ 20736    92160   (ends 112896)
// y1p  bf16 [2br][576wx][676yz][16] @ 131072   24920064 (ends 25051136)
// y2   bf16 [331776 pos][2br][16]   @ 25051136 21233664 (ends 46284800)
#define WP1_OFF   0
#define WP3_OFF   10368
#define WP2F_OFF  20736
#define Y1P_OFF   131072
#define Y1P_PER_BR 12460032
#define Y2_OFF    25051136
#define WS_NEED   46284800ull

// ---------------- prep: pack weights ----------------
__global__ void prep_weights(const float* __restrict__ w1, const float* __restrict__ w2,
                             const float* __restrict__ w3,
                             float* __restrict__ Wp1, float* __restrict__ Wp3,
                             ushort* __restrict__ Wp2f) {
    const int tid = threadIdx.x;
    for (int i = tid; i < 2 * 81 * 16; i += 256) {
        int co = i & 15, t = (i >> 4) % 81, br = i / (81 * 16);
        int ts = br ? permtap(t) : t;
        Wp1[i] = w1[co * 81 + ts];
        Wp3[i] = w3[co * 81 + ts];   // for Wp3, "co" is really ci (w3: [1][16][81])
    }
    for (int i = tid; i < 46080; i += 256) {
        int j = i & 7, l = (i >> 3) & 63, idx = i >> 9;
        int s = idx % 5, ph = (idx / 5) % 9, br = idx / 45;
        int tapl = 2 * s + (l >> 5);
        int co = l & 15, ci = ((l >> 4) & 1) * 8 + j;
        ushort v = 0;
        if (tapl < 9) {
            int dw = ph / 3, dx = ph % 3, dy = tapl / 3, dz = tapl % 3;
            int t = dw * 27 + dx * 9 + dy * 3 + dz;
            int ts = br ? permtap(t) : t;
            v = (ushort)f2bf(w2[(co * 16 + ci) * 81 + ts]);
        }
        Wp2f[i] = v;
    }
}

// ---------------- zero fill (y1p halo init, both branches) ----------------
__global__ void zero_ws(uint4* __restrict__ p, int n4) {
    int i = blockIdx.x * blockDim.x + threadIdx.x;
    int stride = gridDim.x * blockDim.x;
    for (; i < n4; i += stride) p[i] = make_uint4(0u, 0u, 0u, 0u);
}

// ---------------- conv1: x (1ch f32) -> y1p (16ch bf16, padded); 2 br ------
__global__ __launch_bounds__(576) void conv1_plane(
    const float* __restrict__ xn, const float* __restrict__ Wp1g,
    const float* __restrict__ b1, uint32_t* __restrict__ y1p0) {
    __shared__ float xl[9 * 676];
    const int tid = threadIdx.x;
    const int br = blockIdx.x / 576, pb = blockIdx.x % 576;
    const float* Wb = Wp1g + br * 1296;
    uint32_t* y1p = y1p0 + (size_t)br * (Y1P_PER_BR / 4);
    const int w = pb / 24, xx = pb % 24;
    for (int g = tid; g < 6084; g += 576) {
        int wi = g / 2028, r1 = g - wi * 2028;
        int xi = r1 / 676, r2 = r1 - xi * 676;
        int yp = r2 / 26, zp = r2 - yp * 26;
        int ws_ = w + wi - 1, xs = xx + xi - 1, ys = yp - 1, zs = zp - 1;
        float v = 0.f;
        if ((unsigned)ws_ < 24u && (unsigned)xs < 24u && (unsigned)ys < 24u && (unsigned)zs < 24u)
            v = xn[((ws_ * 24 + xs) * 24 + ys) * 24 + zs];
        xl[g] = v;
    }
    __syncthreads();
    const int yy = tid / 24, zz = tid - yy * 24;
    float acc[16];
#pragma unroll
    for (int c = 0; c < 16; ++c) acc[c] = 0.f;
#pragma unroll 1
    for (int dw = 0; dw < 3; ++dw)
#pragma unroll 1
        for (int dx = 0; dx < 3; ++dx) {
            const float* xp = &xl[(dw * 3 + dx) * 676];
#pragma unroll
            for (int dy = 0; dy < 3; ++dy)
#pragma unroll
                for (int dz = 0; dz < 3; ++dz) {
                    float xv = xp[(yy + dy) * 26 + (zz + dz)];
                    const float* wt = &Wb[(((dw * 3 + dx) * 3 + dy) * 3 + dz) << 4];
#pragma unroll
                    for (int c = 0; c < 16; ++c) acc[c] = fmaf(xv, wt[c], acc[c]);
                }
        }
    uint32_t pk[8];
#pragma unroll
    for (int cp = 0; cp < 8; ++cp) {
        float a = fmaxf(acc[2 * cp]     + b1[2 * cp],     0.f);
        float b = fmaxf(acc[2 * cp + 1] + b1[2 * cp + 1], 0.f);
        pk[cp] = f2bf(a) | (f2bf(b) << 16);
    }
    uint32_t* dst = y1p + ((size_t)((w * 24 + xx) * 26 + yy + 1) * 26 + zz + 1) * 8;
    *(uint4*)dst       = make_uint4(pk[0], pk[1], pk[2], pk[3]);
    *(uint4*)(dst + 4) = make_uint4(pk[4], pk[5], pk[6], pk[7]);
}

// ---------------- conv2: MFMA implicit GEMM; 2 br per dispatch -------------
#define RING_STRIDE 17600
#define B_OFF 12480

__global__ __launch_bounds__(256) void conv2_mfma(
    const char* __restrict__ y1p0, const char* __restrict__ Wp2f0,
    const float* __restrict__ b2, ushort* __restrict__ y2n) {
    __shared__ char lds[2 * RING_STRIDE];
    const int tid = threadIdx.x, lane = tid & 63, wid = tid >> 6;
    const int bid = blockIdx.x;
    const int wg = (bid & 7) * 432 + (bid >> 3);        // XCD-chunked swizzle
    const int br = wg / 1728, b = wg - br * 1728;
    const char* y1p = y1p0 + (size_t)br * Y1P_PER_BR;
    const char* Wp2f_br = Wp2f0 + br * 46080;
    ushort* y2b = y2n + br * 16;
    const int w = b / 72, r0 = b % 72, xx = r0 / 3, y0 = (r0 % 3) * 8;

    const int h = (lane >> 4) & 1;
    const bool th = lane >= 32;
    const int pyA = (lane >> 3) & 1, pzA = lane & 7;
    int aoffs[9];
#pragma unroll
    for (int t = 0; t < 9; ++t) {
        int dy = t / 3, dz = t % 3;
        aoffs[t] = ((2 * wid + pyA + dy) * 26 + (pzA + dz)) * 48 + h * 16;
    }
    f32x4 acc[3];
#pragma unroll
    for (int m = 0; m < 3; ++m) acc[m] = f32x4{0.f, 0.f, 0.f, 0.f};

#define STAGE(ph_, rb_) do {                                                        \
    int dw_ = (ph_) / 3, dx_ = (ph_) % 3;                                           \
    int wc_ = min(max(w + dw_ - 1, 0), 23), xc_ = min(max(xx + dx_ - 1, 0), 23);    \
    const char* inpl_ = y1p + (size_t)((wc_ * 24 + xc_) * 676 + y0 * 26) * 32;      \
    const char* wsl_  = Wp2f_br + (ph_) * 5120;                                     \
    _Pragma("unroll")                                                               \
    for (int it_ = 0; it_ < 5; ++it_) {                                             \
        int g_ = tid + it_ * 256;                                                   \
        if (g_ < 1100) {                                                            \
            int row_ = g_ / 3, part_ = g_ - row_ * 3;                               \
            const char* src_ = (g_ < 780)                                           \
                ? (inpl_ + row_ * 32 + (part_ & 1) * 16)                            \
                : (wsl_ + (g_ - 780) * 16);                                         \
            __builtin_amdgcn_global_load_lds(                                       \
                (const __attribute__((address_space(1))) void*)src_,                \
                (__attribute__((address_space(3))) void*)                           \
                    (lds + (rb_) + ((tid & ~63) + it_ * 256) * 16),                 \
                16, 0, 0);                                                          \
        }                                                                           \
    }                                                                               \
} while (0)

    STAGE(0, 0);
    int ring = 0;
#pragma unroll 1
    for (int ph = 0; ph < 9; ++ph) {
        __syncthreads();
        if (ph < 8) STAGE(ph + 1, ring ^ RING_STRIDE);
        int dw = ph / 3, dx = ph % 3;
        bool valid = ((unsigned)(w + dw - 1) < 24u) && ((unsigned)(xx + dx - 1) < 24u);
        if (valid) {
#pragma unroll
            for (int s = 0; s < 5; ++s) {
                i32x4 bvr = *(const i32x4*)(lds + ring + B_OFF + s * 1024 + lane * 16);
                int t0 = aoffs[2 * s];
                int t1 = aoffs[(2 * s + 1 < 9) ? (2 * s + 1) : 8];
                int asel = th ? t1 : t0;
                const char* ap = lds + ring + asel;
#pragma unroll
                for (int m = 0; m < 3; ++m) {
                    i32x4 avr = *(const i32x4*)(ap + m * 384);
                    acc[m] = __builtin_amdgcn_mfma_f32_16x16x32_bf16(
                        __builtin_bit_cast(bf16x8, avr),
                        __builtin_bit_cast(bf16x8, bvr), acc[m], 0, 0, 0);
                }
            }
        }
        ring ^= RING_STRIDE;
    }
#undef STAGE

    // epilogue: D row p=(lane>>4)*4+r, col=lane&15; y2 record stride 32 ushorts
    const int co = lane & 15;
    const float bb = b2[co];
    const int py = (lane >> 5) & 1, c4 = ((lane >> 4) & 1) * 4;
    const size_t rowb = ((size_t)(w * 24 + xx) * 24 + (y0 + 2 * wid + py)) * 24;
#pragma unroll
    for (int m = 0; m < 3; ++m)
#pragma unroll
        for (int r = 0; r < 4; ++r) {
            float v = fmaxf(acc[m][r] + bb, 0.f);
            y2b[(rowb + m * 8 + c4 + r) * 32 + co] = (ushort)f2bf(v);
        }
}

// ---------------- conv3: plane-blocked, LDS-staged --------------------------
__device__ __forceinline__ float dot16(uint4 u0, uint4 u1, const float* __restrict__ wt, float a) {
    a = fmaf(bflo(u0.x), wt[0], a);  a = fmaf(bfhi(u0.x), wt[1], a);
    a = fmaf(bflo(u0.y), wt[2], a);  a = fmaf(bfhi(u0.y), wt[3], a);
    a = fmaf(bflo(u0.z), wt[4], a);  a = fmaf(bfhi(u0.z), wt[5], a);
    a = fmaf(bflo(u0.w), wt[6], a);  a = fmaf(bfhi(u0.w), wt[7], a);
    a = fmaf(bflo(u1.x), wt[8], a);  a = fmaf(bfhi(u1.x), wt[9], a);
    a = fmaf(bflo(u1.y), wt[10], a); a = fmaf(bfhi(u1.y), wt[11], a);
    a = fmaf(bflo(u1.z), wt[12], a); a = fmaf(bfhi(u1.z), wt[13], a);
    a = fmaf(bflo(u1.w), wt[14], a); a = fmaf(bfhi(u1.w), wt[15], a);
    return a;
}

// block = output (w,x) plane (XCD-swizzled); 576 threads = one (y,z) output.
// LDS plane: 26x26 cells of 80B (64B = [2br][16ch] bf16, 16B pad for banks).
__global__ __launch_bounds__(576) void conv3_plane2(
    const char* __restrict__ y2n, const float* __restrict__ Wp3g,
    const float* __restrict__ b3, float* __restrict__ outn) {
    __shared__ char P[26 * 26 * 80];       // 54080 B
    __shared__ float Wl[2 * 81 * 16];      // 10368 B
    const int tid = threadIdx.x;
    const int bid = blockIdx.x;
    const int wg = (bid & 7) * 72 + (bid >> 3);   // bijective XCD swizzle (576%8==0)
    const int w = wg / 24, xx = wg % 24;

    for (int i = tid; i < 2592; i += 576) Wl[i] = Wp3g[i];
    // zero halo border cells (y in {0,25} or z in {0,25}): 100 cells x 64B
    for (int i = tid; i < 400; i += 576) {
        int cell = i >> 2, part = i & 3, cy, cz;
        if (cell < 26)      { cy = 0;  cz = cell; }
        else if (cell < 52) { cy = 25; cz = cell - 26; }
        else if (cell < 76) { cy = cell - 51; cz = 0; }   // y 1..24
        else                { cy = cell - 75; cz = 25; }  // y 1..24
        *(uint4*)(P + (cy * 26 + cz) * 80 + part * 16) = make_uint4(0u, 0u, 0u, 0u);
    }
    // phase-invariant staging offsets: 2304 granules of 16B, 4 per thread
    int goff[4], loff[4];
#pragma unroll
    for (int it = 0; it < 4; ++it) {
        int g = tid + it * 576;
        int yy_ = g / 96, rem = g - yy_ * 96, zz_ = rem >> 2, part = rem & 3;
        goff[it] = g * 16;
        loff[it] = ((yy_ + 1) * 26 + (zz_ + 1)) * 80 + part * 16;
    }
    const int yy = tid / 24, zz = tid - (tid / 24) * 24;
    float a0 = 0.f, a1 = 0.f;
    const float* WB0 = Wl;
    const float* WB1 = Wl + 1296;

#pragma unroll 1
    for (int ph = 0; ph < 9; ++ph) {
        const int dw = ph / 3, dx = ph % 3;
        const int ws_ = w + dw - 1, xs = xx + dx - 1;
        const bool pv = ((unsigned)ws_ < 24u) & ((unsigned)xs < 24u);  // block-uniform
        if (pv) {
            __syncthreads();                       // prev compute done
            const char* src = y2n + (size_t)(ws_ * 24 + xs) * 36864;
            uint4 r0 = *(const uint4*)(src + goff[0]);
            uint4 r1 = *(const uint4*)(src + goff[1]);
            uint4 r2 = *(const uint4*)(src + goff[2]);
            uint4 r3 = *(const uint4*)(src + goff[3]);
            *(uint4*)(P + loff[0]) = r0;
            *(uint4*)(P + loff[1]) = r1;
            *(uint4*)(P + loff[2]) = r2;
            *(uint4*)(P + loff[3]) = r3;
            __syncthreads();                       // plane (and W/border) ready
            const int tb = ph * 9;
#pragma unroll
            for (int dy = 0; dy < 3; ++dy)
#pragma unroll
                for (int dz = 0; dz < 3; ++dz) {
                    const char* cp = P + ((yy + dy) * 26 + (zz + dz)) * 80;
                    uint4 u0 = *(const uint4*)(cp);
                    uint4 u1 = *(const uint4*)(cp + 16);
                    uint4 v0 = *(const uint4*)(cp + 32);
                    uint4 v1 = *(const uint4*)(cp + 48);
                    const int t = tb + dy * 3 + dz;
                    a0 = dot16(u0, u1, &WB0[t << 4], a0);
                    a1 = dot16(v0, v1, &WB1[t << 4], a1);
                }
        }
    }
    const float bias = b3[0];
    outn[((w * 24 + xx) * 24 + yy) * 24 + zz] =
        fmaxf(a0 + bias, 0.f) + fmaxf(a1 + bias, 0.f);
}

extern "C" void kernel_launch(void* const* d_in, const int* in_sizes, int n_in,
                              void* d_out, int out_size, void* d_ws, size_t ws_size,
                              hipStream_t stream) {
    const float* x  = (const float*)d_in[0];
    const float* w1 = (const float*)d_in[1];
    const float* b1 = (const float*)d_in[2];
    const float* w2 = (const float*)d_in[3];
    const float* b2 = (const float*)d_in[4];
    const float* w3 = (const float*)d_in[5];
    const float* b3 = (const float*)d_in[6];
    float* out = (float*)d_out;
    char* ws = (char*)d_ws;
    if (ws_size < WS_NEED) return;

    float*  Wp1  = (float*)(ws + WP1_OFF);
    float*  Wp3  = (float*)(ws + WP3_OFF);
    ushort* Wp2f = (ushort*)(ws + WP2F_OFF);
    uint32_t* y1p_u32 = (uint32_t*)(ws + Y1P_OFF);
    const char* y1p_b = (const char*)(ws + Y1P_OFF);
    ushort* y2 = (ushort*)(ws + Y2_OFF);

    prep_weights<<<1, 256, 0, stream>>>(w1, w2, w3, Wp1, Wp3, Wp2f);
    zero_ws<<<1024, 256, 0, stream>>>((uint4*)(ws + Y1P_OFF), 2 * Y1P_PER_BR / 16);

    for (int n = 0; n < 8; ++n) {
        conv1_plane<<<1152, 576, 0, stream>>>(
            x + (size_t)n * S4, Wp1, b1, y1p_u32);
        conv2_mfma<<<3456, 256, 0, stream>>>(
            y1p_b, (const char*)(ws + WP2F_OFF), b2, y2);
        conv3_plane2<<<576, 576, 0, stream>>>(
            (const char*)y2, Wp3, b3, out + (size_t)n * S4);
    }
}

// Round 5
// 1157.398 us; speedup vs baseline: 7.2184x; 1.6704x over previous
//
#include <hip/hip_runtime.h>
#include <hip/hip_bf16.h>
#include <stdint.h>

// ---------------------------------------------------------------------------
// out = net(x) + P(net(P(x))), P = swap (W,X)<->(Y,Z).  Equivariance:
// P(net(P(x);W)) = net(x; P_w(W)) -> one network, 2 weight branches.
//
// Round 5: conv3 -> MFMA (was 66% of runtime on the VALU).  Mapping:
//   K = 32 = [br0 16ci | br1 16ci] per tap;  N: col0 = branch0 conv,
//   col1 = branch1 conv (B cols >=2 zero);  epilogue relu+relu via shfl_xor.
//   y2p: bf16 [24w][24x][26yp][26zp][br0 16|br1 16] (64-B records, halo-pad)
//   A-staging identical to conv2 (80-B LDS cells, dest-linear global_load_lds
//   with source-granule permutation).  LDS 46.8KB -> 3 blocks/CU.
// ---------------------------------------------------------------------------

#define S   24
#define S2  576
#define S3  13824
#define S4  331776

typedef __attribute__((ext_vector_type(8))) short bf16x8;
typedef __attribute__((ext_vector_type(4))) float f32x4;
typedef __attribute__((ext_vector_type(4))) int   i32x4;

__device__ __forceinline__ float bflo(uint32_t u) { return __uint_as_float(u << 16); }
__device__ __forceinline__ float bfhi(uint32_t u) { return __uint_as_float(u & 0xFFFF0000u); }
__device__ __forceinline__ uint32_t f2bf(float f) {            // RNE f32->bf16
    uint32_t u = __float_as_uint(f);
    return (u + 0x7FFFu + ((u >> 16) & 1u)) >> 16;
}
__device__ __forceinline__ int permtap(int t) {                // (kw,kx,ky,kz)->(ky,kz,kw,kx)
    int kw = t / 27, kx = (t / 9) % 3, ky = (t / 3) % 3, kz = t % 3;
    return ky * 27 + kz * 9 + kw * 3 + kx;
}

// ---------------- workspace map (bytes) ----------------
// Wp1  f32  [2br][81][16co]          @ 0        10368
// Wp3c bf16 [2br][81][16ci]          @ 10368    5184    (ends 15552)
// Wp2f bf16 [2br][9ph][5s][64l][8j]  @ 20736    92160   (ends 112896)
// y1p  bf16 [2br][576wx][676yz][16]  @ 131072   24920064 (ends 25051136)
// y2p  bf16 [576wx][676yz][2br*16]   @ 25051136 24920064 (ends 49971200)
#define WP1_OFF   0
#define WP3C_OFF  10368
#define WP2F_OFF  20736
#define Y1P_OFF   131072
#define Y1P_PER_BR 12460032
#define Y2P_OFF   25051136
#define WS_NEED   49971200ull

// ---------------- prep: pack weights ----------------
__global__ void prep_weights(const float* __restrict__ w1, const float* __restrict__ w2,
                             const float* __restrict__ w3,
                             float* __restrict__ Wp1, ushort* __restrict__ Wp3c,
                             ushort* __restrict__ Wp2f) {
    const int tid = threadIdx.x;
    for (int i = tid; i < 2 * 81 * 16; i += 256) {
        int ci = i & 15, t = (i >> 4) % 81, br = i / 1296;
        int ts = br ? permtap(t) : t;
        Wp1[i]  = w1[ci * 81 + ts];                    // [br][t][16co]
        Wp3c[i] = (ushort)f2bf(w3[ci * 81 + ts]);      // [br][t][16ci]
    }
    for (int i = tid; i < 46080; i += 256) {
        int j = i & 7, l = (i >> 3) & 63, idx = i >> 9;
        int s = idx % 5, ph = (idx / 5) % 9, br = idx / 45;
        int tapl = 2 * s + (l >> 5);
        int co = l & 15, ci = ((l >> 4) & 1) * 8 + j;
        ushort v = 0;
        if (tapl < 9) {
            int dw = ph / 3, dx = ph % 3, dy = tapl / 3, dz = tapl % 3;
            int t = dw * 27 + dx * 9 + dy * 3 + dz;
            int ts = br ? permtap(t) : t;
            v = (ushort)f2bf(w2[(co * 16 + ci) * 81 + ts]);
        }
        Wp2f[i] = v;
    }
}

// ---------------- zero fill (y1p + y2p halo init) ----------------
__global__ void zero_ws(uint4* __restrict__ p, int n4) {
    int i = blockIdx.x * blockDim.x + threadIdx.x;
    int stride = gridDim.x * blockDim.x;
    for (; i < n4; i += stride) p[i] = make_uint4(0u, 0u, 0u, 0u);
}

// ---------------- conv1: x (1ch f32) -> y1p (16ch bf16, padded); 2 br ------
__global__ __launch_bounds__(576) void conv1_plane(
    const float* __restrict__ xn, const float* __restrict__ Wp1g,
    const float* __restrict__ b1, uint32_t* __restrict__ y1p0) {
    __shared__ float xl[9 * 676];
    const int tid = threadIdx.x;
    const int br = blockIdx.x / 576, pb = blockIdx.x % 576;
    const float* Wb = Wp1g + br * 1296;
    uint32_t* y1p = y1p0 + (size_t)br * (Y1P_PER_BR / 4);
    const int w = pb / 24, xx = pb % 24;
    for (int g = tid; g < 6084; g += 576) {
        int wi = g / 2028, r1 = g - wi * 2028;
        int xi = r1 / 676, r2 = r1 - xi * 676;
        int yp = r2 / 26, zp = r2 - yp * 26;
        int ws_ = w + wi - 1, xs = xx + xi - 1, ys = yp - 1, zs = zp - 1;
        float v = 0.f;
        if ((unsigned)ws_ < 24u && (unsigned)xs < 24u && (unsigned)ys < 24u && (unsigned)zs < 24u)
            v = xn[((ws_ * 24 + xs) * 24 + ys) * 24 + zs];
        xl[g] = v;
    }
    __syncthreads();
    const int yy = tid / 24, zz = tid - yy * 24;
    float acc[16];
#pragma unroll
    for (int c = 0; c < 16; ++c) acc[c] = 0.f;
#pragma unroll 1
    for (int dw = 0; dw < 3; ++dw)
#pragma unroll 1
        for (int dx = 0; dx < 3; ++dx) {
            const float* xp = &xl[(dw * 3 + dx) * 676];
#pragma unroll
            for (int dy = 0; dy < 3; ++dy)
#pragma unroll
                for (int dz = 0; dz < 3; ++dz) {
                    float xv = xp[(yy + dy) * 26 + (zz + dz)];
                    const float* wt = &Wb[(((dw * 3 + dx) * 3 + dy) * 3 + dz) << 4];
#pragma unroll
                    for (int c = 0; c < 16; ++c) acc[c] = fmaf(xv, wt[c], acc[c]);
                }
        }
    uint32_t pk[8];
#pragma unroll
    for (int cp = 0; cp < 8; ++cp) {
        float a = fmaxf(acc[2 * cp]     + b1[2 * cp],     0.f);
        float b = fmaxf(acc[2 * cp + 1] + b1[2 * cp + 1], 0.f);
        pk[cp] = f2bf(a) | (f2bf(b) << 16);
    }
    uint32_t* dst = y1p + ((size_t)((w * 24 + xx) * 26 + yy + 1) * 26 + zz + 1) * 8;
    *(uint4*)dst       = make_uint4(pk[0], pk[1], pk[2], pk[3]);
    *(uint4*)(dst + 4) = make_uint4(pk[4], pk[5], pk[6], pk[7]);
}

// ---------------- conv2: MFMA implicit GEMM; 2 br per dispatch -------------
#define RING_STRIDE 17600
#define B_OFF 12480

__global__ __launch_bounds__(256) void conv2_mfma(
    const char* __restrict__ y1p0, const char* __restrict__ Wp2f0,
    const float* __restrict__ b2, ushort* __restrict__ y2p) {
    __shared__ char lds[2 * RING_STRIDE];
    const int tid = threadIdx.x, lane = tid & 63, wid = tid >> 6;
    const int bid = blockIdx.x;
    const int wg = (bid & 7) * 432 + (bid >> 3);        // XCD-chunked swizzle
    const int br = wg / 1728, b = wg - br * 1728;
    const char* y1p = y1p0 + (size_t)br * Y1P_PER_BR;
    const char* Wp2f_br = Wp2f0 + br * 46080;
    ushort* y2b = y2p + br * 16;
    const int w = b / 72, r0 = b % 72, xx = r0 / 3, y0 = (r0 % 3) * 8;

    const int h = (lane >> 4) & 1;
    const bool th = lane >= 32;
    const int pyA = (lane >> 3) & 1, pzA = lane & 7;
    int aoffs[9];
#pragma unroll
    for (int t = 0; t < 9; ++t) {
        int dy = t / 3, dz = t % 3;
        aoffs[t] = ((2 * wid + pyA + dy) * 26 + (pzA + dz)) * 48 + h * 16;
    }
    f32x4 acc[3];
#pragma unroll
    for (int m = 0; m < 3; ++m) acc[m] = f32x4{0.f, 0.f, 0.f, 0.f};

#define STAGE(ph_, rb_) do {                                                        \
    int dw_ = (ph_) / 3, dx_ = (ph_) % 3;                                           \
    int wc_ = min(max(w + dw_ - 1, 0), 23), xc_ = min(max(xx + dx_ - 1, 0), 23);    \
    const char* inpl_ = y1p + (size_t)((wc_ * 24 + xc_) * 676 + y0 * 26) * 32;      \
    const char* wsl_  = Wp2f_br + (ph_) * 5120;                                     \
    _Pragma("unroll")                                                               \
    for (int it_ = 0; it_ < 5; ++it_) {                                             \
        int g_ = tid + it_ * 256;                                                   \
        if (g_ < 1100) {                                                            \
            int row_ = g_ / 3, part_ = g_ - row_ * 3;                               \
            const char* src_ = (g_ < 780)                                           \
                ? (inpl_ + row_ * 32 + (part_ & 1) * 16)                            \
                : (wsl_ + (g_ - 780) * 16);                                         \
            __builtin_amdgcn_global_load_lds(                                       \
                (const __attribute__((address_space(1))) void*)src_,                \
                (__attribute__((address_space(3))) void*)                           \
                    (lds + (rb_) + ((tid & ~63) + it_ * 256) * 16),                 \
                16, 0, 0);                                                          \
        }                                                                           \
    }                                                                               \
} while (0)

    STAGE(0, 0);
    int ring = 0;
#pragma unroll 1
    for (int ph = 0; ph < 9; ++ph) {
        __syncthreads();
        if (ph < 8) STAGE(ph + 1, ring ^ RING_STRIDE);
        int dw = ph / 3, dx = ph % 3;
        bool valid = ((unsigned)(w + dw - 1) < 24u) && ((unsigned)(xx + dx - 1) < 24u);
        if (valid) {
#pragma unroll
            for (int s = 0; s < 5; ++s) {
                i32x4 bvr = *(const i32x4*)(lds + ring + B_OFF + s * 1024 + lane * 16);
                int t0 = aoffs[2 * s];
                int t1 = aoffs[(2 * s + 1 < 9) ? (2 * s + 1) : 8];
                int asel = th ? t1 : t0;
                const char* ap = lds + ring + asel;
#pragma unroll
                for (int m = 0; m < 3; ++m) {
                    i32x4 avr = *(const i32x4*)(ap + m * 384);
                    acc[m] = __builtin_amdgcn_mfma_f32_16x16x32_bf16(
                        __builtin_bit_cast(bf16x8, avr),
                        __builtin_bit_cast(bf16x8, bvr), acc[m], 0, 0, 0);
                }
            }
        }
        ring ^= RING_STRIDE;
    }
#undef STAGE

    // epilogue into padded y2p: record = plane*676 + (y+1)*26 + (z+1)
    const int co = lane & 15;
    const float bb = b2[co];
    const int py = (lane >> 5) & 1, c4 = ((lane >> 4) & 1) * 4;
    const size_t planeb = (size_t)(w * 24 + xx) * 676;
    const size_t rowb = planeb + (size_t)(y0 + 2 * wid + py + 1) * 26 + 1;
#pragma unroll
    for (int m = 0; m < 3; ++m)
#pragma unroll
        for (int r = 0; r < 4; ++r) {
            float v = fmaxf(acc[m][r] + bb, 0.f);
            y2b[(rowb + m * 8 + c4 + r) * 32 + co] = (ushort)f2bf(v);
        }
}

// ---------------- conv3: MFMA, branches in N cols 0/1 ----------------------
// grid 1728 = 24w x 24x x 3yg (XCD-swizzled); block 256 = 4 waves.
// LDS: A-ring 2 x 20800 (260 cells of 80B per buffer) + w3c 5184.
#define RING3   20800
#define W3C_LDS 41600

__global__ __launch_bounds__(256) void conv3_mfma(
    const char* __restrict__ y2p, const char* __restrict__ Wp3c,
    const float* __restrict__ b3, float* __restrict__ outn) {
    __shared__ char lds[2 * RING3 + 5184];
    const int tid = threadIdx.x, lane = tid & 63, wid = tid >> 6;
    const int bid = blockIdx.x;
    const int wg = (bid & 7) * 216 + (bid >> 3);        // bijective (1728%8==0)
    const int w = wg / 72, r0 = wg % 72, xx = r0 / 3, y0 = (r0 % 3) * 8;

    const int col = lane & 15, g16 = (lane >> 4) & 3;
    const int pyA = (lane >> 3) & 1, pzA = lane & 7;
    int a3[9];
#pragma unroll
    for (int t = 0; t < 9; ++t) {
        int dy = t / 3, dz = t % 3;
        a3[t] = ((2 * wid + pyA + dy) * 26 + (pzA + dz)) * 80 + g16 * 16;
    }
    // B lane constants: col0 <- br0 rows (k<16), col1 <- br1 rows (k>=16)
    const bool bact = (col == 0 && g16 < 2) || (col == 1 && g16 >= 2);
    const int colsel = (col < 2) ? col : 0;
    const int b_base = W3C_LDS + colsel * 2592 + (g16 & 1) * 16;
    const int bmask = bact ? -1 : 0;

    // one-time B stage: 324 granules of 16B
#pragma unroll
    for (int it = 0; it < 2; ++it) {
        int g = tid + it * 256;
        if (g < 324)
            __builtin_amdgcn_global_load_lds(
                (const __attribute__((address_space(1))) void*)(Wp3c + g * 16),
                (__attribute__((address_space(3))) void*)
                    (lds + W3C_LDS + ((tid & ~63) + it * 256) * 16),
                16, 0, 0);
    }

    f32x4 acc[3];
#pragma unroll
    for (int m = 0; m < 3; ++m) acc[m] = f32x4{0.f, 0.f, 0.f, 0.f};

// A slab: 10 y-rows x 26 zp x 64B -> LDS cells of 80B (dest-linear, src-permuted)
#define STAGE3(ph_, rb_) do {                                                       \
    int dw_ = (ph_) / 3, dx_ = (ph_) % 3;                                           \
    int wc_ = min(max(w + dw_ - 1, 0), 23), xc_ = min(max(xx + dx_ - 1, 0), 23);    \
    const char* slab_ = y2p + (size_t)((wc_ * 24 + xc_) * 676 + y0 * 26) * 64;      \
    _Pragma("unroll")                                                               \
    for (int it_ = 0; it_ < 6; ++it_) {                                             \
        int g_ = tid + it_ * 256;                                                   \
        if (g_ < 1300) {                                                            \
            int c_ = g_ / 5, p_ = g_ - c_ * 5;                                      \
            if (p_ < 4)                                                             \
                __builtin_amdgcn_global_load_lds(                                   \
                    (const __attribute__((address_space(1))) void*)                 \
                        (slab_ + c_ * 64 + p_ * 16),                                \
                    (__attribute__((address_space(3))) void*)                       \
                        (lds + (rb_) + ((tid & ~63) + it_ * 256) * 16),             \
                    16, 0, 0);                                                      \
        }                                                                           \
    }                                                                               \
} while (0)

    STAGE3(0, 0);
    int ring = 0;
#pragma unroll 1
    for (int ph = 0; ph < 9; ++ph) {
        __syncthreads();
        if (ph < 8) STAGE3(ph + 1, ring ^ RING3);
        int dw = ph / 3, dx = ph % 3;
        bool valid = ((unsigned)(w + dw - 1) < 24u) && ((unsigned)(xx + dx - 1) < 24u);
        if (valid) {
#pragma unroll
            for (int tl = 0; tl < 9; ++tl) {
                int tap = ph * 9 + tl;
                i32x4 braw = *(const i32x4*)(lds + b_base + tap * 32);
                i32x4 bm;
                bm[0] = braw[0] & bmask; bm[1] = braw[1] & bmask;
                bm[2] = braw[2] & bmask; bm[3] = braw[3] & bmask;
#pragma unroll
                for (int m = 0; m < 3; ++m) {
                    i32x4 avr = *(const i32x4*)(lds + ring + a3[tl] + m * 640);
                    acc[m] = __builtin_amdgcn_mfma_f32_16x16x32_bf16(
                        __builtin_bit_cast(bf16x8, avr),
                        __builtin_bit_cast(bf16x8, bm), acc[m], 0, 0, 0);
                }
            }
        }
        ring ^= RING3;
    }
#undef STAGE3

    // epilogue: col0 lanes combine with col1 via shfl_xor(1); float4 z-stores
    const float bv = b3[0];
    const int py = (lane >> 5) & 1, c4 = ((lane >> 4) & 1) * 4;
    const int yo = y0 + 2 * wid + py;
    float* obase = outn + ((size_t)(w * 24 + xx) * 24 + yo) * 24;
#pragma unroll
    for (int m = 0; m < 3; ++m) {
        float o[4];
#pragma unroll
        for (int r = 0; r < 4; ++r) {
            float mine = acc[m][r];
            float oth = __shfl_xor(mine, 1);
            o[r] = fmaxf(mine + bv, 0.f) + fmaxf(oth + bv, 0.f);
        }
        if (col == 0)
            *(float4*)(obase + m * 8 + c4) = make_float4(o[0], o[1], o[2], o[3]);
    }
}

extern "C" void kernel_launch(void* const* d_in, const int* in_sizes, int n_in,
                              void* d_out, int out_size, void* d_ws, size_t ws_size,
                              hipStream_t stream) {
    const float* x  = (const float*)d_in[0];
    const float* w1 = (const float*)d_in[1];
    const float* b1 = (const float*)d_in[2];
    const float* w2 = (const float*)d_in[3];
    const float* b2 = (const float*)d_in[4];
    const float* w3 = (const float*)d_in[5];
    const float* b3 = (const float*)d_in[6];
    float* out = (float*)d_out;
    char* ws = (char*)d_ws;
    if (ws_size < WS_NEED) return;

    float*  Wp1  = (float*)(ws + WP1_OFF);
    ushort* Wp3c = (ushort*)(ws + WP3C_OFF);
    ushort* Wp2f = (ushort*)(ws + WP2F_OFF);
    uint32_t* y1p_u32 = (uint32_t*)(ws + Y1P_OFF);
    const char* y1p_b = (const char*)(ws + Y1P_OFF);
    ushort* y2p = (ushort*)(ws + Y2P_OFF);

    prep_weights<<<1, 256, 0, stream>>>(w1, w2, w3, Wp1, Wp3c, Wp2f);
    zero_ws<<<2048, 256, 0, stream>>>((uint4*)(ws + Y1P_OFF),
                                      (int)((WS_NEED - Y1P_OFF) / 16));

    for (int n = 0; n < 8; ++n) {
        conv1_plane<<<1152, 576, 0, stream>>>(
            x + (size_t)n * S4, Wp1, b1, y1p_u32);
        conv2_mfma<<<3456, 256, 0, stream>>>(
            y1p_b, (const char*)(ws + WP2F_OFF), b2, y2p);
        conv3_mfma<<<1728, 256, 0, stream>>>(
            (const char*)y2p, (const char*)(ws + WP3C_OFF), b3,
            out + (size_t)n * S4);
    }
}